// Round 8
// baseline (834.668 us; speedup 1.0000x reference)
//
#include <hip/hip_runtime.h>
#include <stdint.h>

typedef uint16_t u16;
typedef short short8 __attribute__((ext_vector_type(8)));
typedef float f32x16 __attribute__((ext_vector_type(16)));

__device__ __forceinline__ u16 f2bf(float f){
  uint32_t u = __float_as_uint(f);
  u += 0x7fff + ((u >> 16) & 1);   // RNE
  return (u16)(u >> 16);
}

__device__ __forceinline__ void gload_lds16(const u16* g, const char* l){
  __builtin_amdgcn_global_load_lds((const __attribute__((address_space(1))) void*)g,
                                   (__attribute__((address_space(3))) void*)l,
                                   16, 0, 0);
}

// ---- prep: fp32 -> bf16 cast (vectorized, 8 elems/thread/iter) ----
__global__ void cast_bf16_kernel(const float* __restrict__ src, u16* __restrict__ dst, long n8){
  long i = (long)blockIdx.x * blockDim.x + threadIdx.x;
  long stride = (long)gridDim.x * blockDim.x;
  for (; i < n8; i += stride){
    float4 a = *(const float4*)(src + i*8);
    float4 b = *(const float4*)(src + i*8 + 4);
    u16 r[8] = {f2bf(a.x), f2bf(a.y), f2bf(a.z), f2bf(a.w),
                f2bf(b.x), f2bf(b.y), f2bf(b.z), f2bf(b.w)};
    *(uint4*)(dst + i*8) = *(const uint4*)r;
  }
}

// ---- prep: L = tril(pre) cast to bf16 ; layout (n,u,v) 8x512x512 ----
__global__ void mask_cast_L_kernel(const float* __restrict__ pre, u16* __restrict__ L){
  long i = (long)blockIdx.x * blockDim.x + threadIdx.x;  // chunk of 8 along v
  if (i >= 8L*512*64) return;
  int v0 = (int)(i & 63) * 8;
  int u  = (int)((i >> 6) & 511);
  float4 a = *(const float4*)(pre + i*8);
  float4 b = *(const float4*)(pre + i*8 + 4);
  float vals[8] = {a.x,a.y,a.z,a.w,b.x,b.y,b.z,b.w};
  u16 r[8];
  #pragma unroll
  for (int j=0;j<8;j++) r[j] = f2bf((v0 + j <= u) ? vals[j] : 0.0f);
  *(uint4*)(L + i*8) = *(const uint4*)r;
}

// ---- 4-wave 32x32-MFMA NT GEMM: C[M,N] = A(MxK,rm) * B(NxK,rm)^T ----
// 256x256 tile, BK=32, 4 waves (2Mx2N), wave tile 128x128, acc[4][4] f32x16
// (256 VGPR, 1 wave/SIMD). LDS reads 64KB/K-tile (each frag read by 2 waves)
// vs 96KB at 8 waves -> MFMA-bound. v_mfma_f32_32x32x16_bf16 (2495 TF shape).
// 4 LDS buffers (32KB: A 16KB + B 16KB, 64B rows), stage 3 ahead, vmcnt(8),
// one barrier per K-tile. Per K-tile 2 half-phases:
//   {read ks1(j) frags -> MMA ks0} {read ks0(j+1) + stage(j+3) -> MMA ks1}
// reads precede MFMA clusters (in-order issue overlap), sched_barrier pins.
// Swizzle: phys_chunk = c ^ (row&3) on 16B chunks; reads conflict-free
// (each bank exactly 8x per b128); applied on pre-swizzled global source
// (linear gload_lds dest) and on ds_read address (both-sides involution).
// SWZ: XCD-chunked remap of the full linearized grid (nwg % 8 == 0).
// tri: 1 = skip blocks above diagonal (S); 2 = Keff=row0+256 (O).
// EPI: 0 bf16; 1 +bias[row] bf16; 2 tril*scale bf16; 3 +bias[col] fp32.
template<int EPI, bool SWZ>
__global__ __launch_bounds__(256, 1)
void gemm4w(const u16* __restrict__ A, const u16* __restrict__ B,
            void* __restrict__ Cv, int K, int lda, int ldb, int ldc,
            long asb, long asn, long bsb, long bsn, long csb, long csn,
            const float* __restrict__ bias, float scale, int tri)
{
  extern __shared__ __align__(16) char smem[];   // 4 * 32768 = 131072 B
  const int t = threadIdx.x;
  const int lane = t & 63;
  const int wave = t >> 6;          // 0..3
  const int wm = wave >> 1;         // 0..1
  const int wn = wave & 1;          // 0..1

  int bx = blockIdx.x, by = blockIdx.y, bz = blockIdx.z;
  if constexpr (SWZ){
    int nbx = gridDim.x, nxy = gridDim.x * gridDim.y;
    int bid = bx + by*nbx + bz*nxy;
    int chunk = (nxy * gridDim.z) >> 3;
    int b2 = (bid & 7) * chunk + (bid >> 3);
    bz = b2 / nxy; int rem = b2 - bz*nxy;
    by = rem / nbx; bx = rem - by*nbx;
  }
  const long zb = bz >> 3, zn = bz & 7;
  A += zb*asb + zn*asn;
  B += zb*bsb + zn*bsn;
  const int row0 = by * 256, col0 = bx * 256;
  const int lr = lane & 31, hi = lane >> 5;

  // staging: thread t -> dest 16B slot (q*4096 + t*16); row = q*64 + (t>>2),
  // phys chunk = t&3; source chunk = phys ^ (row&3) = (t&3) ^ ((t>>2)&3)
  const int srow = t >> 2;                                // 0..63
  const int scol = (((t & 3) ^ ((t >> 2) & 3)) * 8);      // elements
  const u16* gA = A + (long)(row0 + srow)*lda + scol;
  const u16* gB = B + (long)(col0 + srow)*ldb + scol;
  const long a64 = 64L*(long)lda, b64 = 64L*(long)ldb;
  const int t16 = t * 16;

  // frag read offsets (bytes in buffer): row = base + lr, chunk c = ks*2+hi,
  // phys = c ^ (lr&3)  [row&3 == lr&3 since bases are multiples of 32]
  const int sw  = (hi ^ (lr & 3)) * 16;
  const int aof0 = (wm*128 + lr)*64 + sw;          const int aof1 = aof0 ^ 32;
  const int bof0 = 16384 + (wn*128 + lr)*64 + sw;  const int bof1 = bof0 ^ 32;

  f32x16 acc[4][4];
  #pragma unroll
  for (int mb=0;mb<4;mb++)
    #pragma unroll
    for (int nb=0;nb<4;nb++)
      acc[mb][nb] = (f32x16)(0.f);

  int Keff = K;
  if (tri == 2) Keff = (row0 + 256 < K) ? (row0 + 256) : K;
  const int NT = Keff >> 5;                 // 8 / 16 / 128 (mult of 4)
  const bool skipall = (tri == 1) && (col0 >= row0 + 256);  // block-uniform

  if (!skipall){
    short8 afA[4], bfA[4], afB[4], bfB[4];

#define STAGEM(PA, PB, BUF) { \
  const u16* pa_ = (PA); const u16* pb_ = (PB); \
  gload_lds16(pa_,          smem + (BUF)*32768 +         t16); \
  gload_lds16(pa_ +   a64,  smem + (BUF)*32768 +  4096 + t16); \
  gload_lds16(pa_ + 2*a64,  smem + (BUF)*32768 +  8192 + t16); \
  gload_lds16(pa_ + 3*a64,  smem + (BUF)*32768 + 12288 + t16); \
  gload_lds16(pb_,          smem + (BUF)*32768 + 16384 + t16); \
  gload_lds16(pb_ +   b64,  smem + (BUF)*32768 + 20480 + t16); \
  gload_lds16(pb_ + 2*b64,  smem + (BUF)*32768 + 24576 + t16); \
  gload_lds16(pb_ + 3*b64,  smem + (BUF)*32768 + 28672 + t16); }

#define RD_A(D) { \
  _Pragma("unroll") for (int mb=0;mb<4;mb++) afA[mb] = *(const short8*)(smem + (D)*32768 + aof0 + mb*2048); \
  _Pragma("unroll") for (int nb=0;nb<4;nb++) bfA[nb] = *(const short8*)(smem + (D)*32768 + bof0 + nb*2048); }
#define RD_B(D) { \
  _Pragma("unroll") for (int mb=0;mb<4;mb++) afB[mb] = *(const short8*)(smem + (D)*32768 + aof1 + mb*2048); \
  _Pragma("unroll") for (int nb=0;nb<4;nb++) bfB[nb] = *(const short8*)(smem + (D)*32768 + bof1 + nb*2048); }
#define MMA(AF, BF) { \
  _Pragma("unroll") for (int mb=0;mb<4;mb++) \
  _Pragma("unroll") for (int nb=0;nb<4;nb++) \
    acc[mb][nb] = __builtin_amdgcn_mfma_f32_32x32x16_bf16(AF[mb], BF[nb], acc[mb][nb], 0, 0, 0); }

// BODY tile j (D = j&3): half-phase ks0 then ks1; reads issued before each
// MFMA cluster so LDS service overlaps MFMA crunch (in-order issue).
#define BODY(D, DOST, PA, PB, VM) { \
  RD_B(D); \
  __builtin_amdgcn_sched_barrier(0); \
  MMA(afA, bfA); \
  __builtin_amdgcn_sched_barrier(0); \
  RD_A(((D)+1)&3); \
  if (DOST) STAGEM(PA, PB, ((D)+3)&3) \
  __builtin_amdgcn_sched_barrier(0); \
  MMA(afB, bfB); \
  asm volatile("s_waitcnt vmcnt(" VM ")" ::: "memory"); \
  __builtin_amdgcn_s_barrier(); \
  asm volatile("" ::: "memory"); }

    // prologue: stage tiles 0,1,2; ensure 0,1 landed; preload frags(0, ks0)
    STAGEM(gA,      gB,      0)
    STAGEM(gA + 32, gB + 32, 1)
    STAGEM(gA + 64, gB + 64, 2)
    asm volatile("s_waitcnt vmcnt(8)" ::: "memory");
    __builtin_amdgcn_s_barrier();
    asm volatile("" ::: "memory");
    RD_A(0)

    #pragma unroll 1
    for (int tb = 0; tb < NT - 4; tb += 4){
      const u16* pa = gA + (long)(tb + 3)*32;
      const u16* pb = gB + (long)(tb + 3)*32;
      BODY(0, true, pa,      pb,      "8")
      BODY(1, true, pa + 32, pb + 32, "8")
      BODY(2, true, pa + 64, pb + 64, "8")
      BODY(3, true, pa + 96, pb + 96, "8")
    }
    {
      const u16* pa = gA + (long)(NT - 1)*32;
      const u16* pb = gB + (long)(NT - 1)*32;
      BODY(0, true,  pa, pb, "8")
      BODY(1, false, pa, pb, "0")
      BODY(2, false, pa, pb, "0")
      BODY(3, false, pa, pb, "0")
    }
#undef STAGEM
#undef RD_A
#undef RD_B
#undef MMA
#undef BODY
  }

  // epilogue: 32x32 C/D map col=lane&31, row=(reg&3)+8*(reg>>2)+4*(lane>>5)
  if constexpr (EPI == 3){
    float* C = (float*)Cv;
    #pragma unroll
    for (int mb=0;mb<4;mb++){
      int rb = row0 + wm*128 + mb*32 + 4*hi;
      #pragma unroll
      for (int nb=0;nb<4;nb++){
        int c = col0 + wn*128 + nb*32 + lr;
        float bc = bias[c];
        #pragma unroll
        for (int reg=0; reg<16; reg++){
          int r = rb + (reg & 3) + 8*(reg >> 2);
          C[(long)r*ldc + c] = acc[mb][nb][reg] + bc;
        }
      }
    }
  } else {
    u16* C = (u16*)Cv + zb*csb + zn*csn;
    #pragma unroll
    for (int mb=0;mb<4;mb++){
      int rb = row0 + wm*128 + mb*32 + 4*hi;
      #pragma unroll
      for (int nb=0;nb<4;nb++){
        int c = col0 + wn*128 + nb*32 + lr;
        #pragma unroll
        for (int reg=0; reg<16; reg++){
          int r = rb + (reg & 3) + 8*(reg >> 2);
          float v = acc[mb][nb][reg];
          if constexpr (EPI==1) v += bias[r];
          if constexpr (EPI==2) v = (c <= r) ? v*scale : 0.0f;
          C[(long)r*ldc + c] = f2bf(v);
        }
      }
    }
  }
}

// Workspace layout (bytes):
//   xb   @ 0          : 8192x4096 bf16
//   W1b  @ 67108864   : 4096x4096 bf16
//   W2b  @ 100663296  : 4096x4096 bf16
//   Lb   @ 134217728  : 8x512x512 bf16
//   Mb   @ 138412032  : 8x512x512 bf16
//   PtG  @ 142606336  : 4096x8192 bf16   PtG[c][r] = P_full[r][c]
//   MPt  @ 209715200  : 128x512x512 bf16 MPt[z][j][u] = MP[b,n,u,j]
//   Sb   @ 276824064  : 128x512x512 bf16
//   Ob   = MPt (reuse; MPt dead after S-gemm)

#define LDSB 131072

extern "C" void kernel_launch(void* const* d_in, const int* in_sizes, int n_in,
                              void* d_out, int out_size, void* d_ws, size_t ws_size,
                              hipStream_t stream)
{
  (void)in_sizes; (void)n_in; (void)out_size; (void)ws_size;
  const float* x   = (const float*)d_in[0];
  const float* W1  = (const float*)d_in[1];
  const float* b1  = (const float*)d_in[2];
  const float* pre = (const float*)d_in[3];
  const float* W2  = (const float*)d_in[4];
  const float* b2  = (const float*)d_in[5];
  float* out = (float*)d_out;
  char* ws = (char*)d_ws;

  u16* xb  = (u16*)(ws + 0L);
  u16* W1b = (u16*)(ws + 67108864L);
  u16* W2b = (u16*)(ws + 100663296L);
  u16* Lb  = (u16*)(ws + 134217728L);
  u16* Mb  = (u16*)(ws + 138412032L);
  u16* Pt  = (u16*)(ws + 142606336L);
  u16* MPt = (u16*)(ws + 209715200L);
  u16* Sb  = (u16*)(ws + 276824064L);
  u16* Ob  = MPt;  // reuse: MPt consumed by S-gemm before O-gemm writes

  hipFuncSetAttribute((const void*)gemm4w<0,true>, hipFuncAttributeMaxDynamicSharedMemorySize, LDSB);
  hipFuncSetAttribute((const void*)gemm4w<1,true>, hipFuncAttributeMaxDynamicSharedMemorySize, LDSB);
  hipFuncSetAttribute((const void*)gemm4w<2,true>, hipFuncAttributeMaxDynamicSharedMemorySize, LDSB);
  hipFuncSetAttribute((const void*)gemm4w<3,true>, hipFuncAttributeMaxDynamicSharedMemorySize, LDSB);

  // preps
  cast_bf16_kernel<<<4096,256,0,stream>>>(x,  xb,  4194304L);
  cast_bf16_kernel<<<4096,256,0,stream>>>(W1, W1b, 2097152L);
  cast_bf16_kernel<<<4096,256,0,stream>>>(W2, W2b, 2097152L);
  mask_cast_L_kernel<<<1024,256,0,stream>>>(pre, Lb);

  // M[n] = L[n] ·NT· L[n]          (8 batches, 512^3)
  gemm4w<0,true><<<dim3(2,2,8),256,LDSB,stream>>>(Lb, Lb, Mb, 512, 512,512,512,
      0, 262144, 0, 262144, 0, 262144, nullptr, 0.f, 0);

  // PtG = W1b ·NT· xb + b1[row]    (4096 x 8192, K=4096)
  gemm4w<1,true><<<dim3(32,16,1),256,LDSB,stream>>>(W1b, xb, Pt, 4096, 4096,4096,8192,
      0,0, 0,0, 0,0, b1, 0.f, 0);

  // MPt[z] = Pt(b,n) ·NT· M[n]     (128 batches, 512^3)
  gemm4w<0,true><<<dim3(2,2,128),256,LDSB,stream>>>(Pt, Mb, MPt, 512, 8192,512,512,
      512, 512L*8192, 0, 262144, 8L*262144, 262144, nullptr, 0.f, 0);

  // S[z] = Pt(b,n) ·NT· MPt[z], *1/sqrt(512), tril mask; skip upper blocks
  gemm4w<2,true><<<dim3(2,2,128),256,LDSB,stream>>>(Pt, MPt, Sb, 512, 8192,512,512,
      512, 512L*8192, 8L*262144, 262144, 8L*262144, 262144, nullptr, 0.04419417382f, 1);

  // O(b,n) = S[z] ·NT· Pt(b,n) -> Ob; S lower-tri => Keff = row0+256
  gemm4w<0,true><<<dim3(2,2,128),256,LDSB,stream>>>(Sb, Pt, Ob, 512, 512,8192,4096,
      8L*262144, 262144, 512, 512L*8192, 512L*4096, 512, nullptr, 0.f, 2);

  // Y = Ob ·NT· W2b + b2[col]      (8192 x 4096, K=4096, fp32 out)
  gemm4w<3,true><<<dim3(16,32,1),256,LDSB,stream>>>(Ob, W2b, out, 4096, 4096,4096,4096,
      0,0, 0,0, 0,0, b2, 0.f, 0);
}

// Round 10
// 703.147 us; speedup vs baseline: 1.1870x; 1.1870x over previous
//
#include <hip/hip_runtime.h>
#include <stdint.h>

typedef uint16_t u16;
typedef short short8 __attribute__((ext_vector_type(8)));
typedef float f32x4 __attribute__((ext_vector_type(4)));

__device__ __forceinline__ u16 f2bf(float f){
  uint32_t u = __float_as_uint(f);
  u += 0x7fff + ((u >> 16) & 1);   // RNE
  return (u16)(u >> 16);
}

__device__ __forceinline__ void gload_lds16(const u16* g, const char* l){
  __builtin_amdgcn_global_load_lds((const __attribute__((address_space(1))) void*)g,
                                   (__attribute__((address_space(3))) void*)l,
                                   16, 0, 0);
}

// ---- prep: fp32 -> bf16 cast (vectorized, 8 elems/thread/iter) ----
__global__ void cast_bf16_kernel(const float* __restrict__ src, u16* __restrict__ dst, long n8){
  long i = (long)blockIdx.x * blockDim.x + threadIdx.x;
  long stride = (long)gridDim.x * blockDim.x;
  for (; i < n8; i += stride){
    float4 a = *(const float4*)(src + i*8);
    float4 b = *(const float4*)(src + i*8 + 4);
    u16 r[8] = {f2bf(a.x), f2bf(a.y), f2bf(a.z), f2bf(a.w),
                f2bf(b.x), f2bf(b.y), f2bf(b.z), f2bf(b.w)};
    *(uint4*)(dst + i*8) = *(const uint4*)r;
  }
}

// ---- prep: L = tril(pre) cast to bf16 ; layout (n,u,v) 8x512x512 ----
__global__ void mask_cast_L_kernel(const float* __restrict__ pre, u16* __restrict__ L){
  long i = (long)blockIdx.x * blockDim.x + threadIdx.x;  // chunk of 8 along v
  if (i >= 8L*512*64) return;
  int v0 = (int)(i & 63) * 8;
  int u  = (int)((i >> 6) & 511);
  float4 a = *(const float4*)(pre + i*8);
  float4 b = *(const float4*)(pre + i*8 + 4);
  float vals[8] = {a.x,a.y,a.z,a.w,b.x,b.y,b.z,b.w};
  u16 r[8];
  #pragma unroll
  for (int j=0;j<8;j++) r[j] = f2bf((v0 + j <= u) ? vals[j] : 0.0f);
  *(uint4*)(L + i*8) = *(const uint4*)r;
}

// ---- deep-pipelined NT GEMM: C[M,N] = A(MxK,rm) * B(NxK,rm)^T ----
// 256x256 tile, BK=32, 8 waves (2Mx4N), wave 128x64, acc[4+4][4] f32x4.
// 4 LDS buffers (32KB: A[256rows x 64B] + B[256rows x 64B]), stage 3 ahead,
// counted vmcnt(8), one barrier per K-tile, K-loop unrolled 4x.
// Swizzle g(r)=(r>>1)&3 on 16B chunks, both-sides (0 conflicts, verified r4).
// COMPUTE body is the round-4-verified single-K-step form (12 ds_read_b128 +
// 32 MFMA); only delta: stage-issue points S1/S2 between MFMA half-clusters.
// tri: 1 = early-return blocks above the diagonal (S-gemm; output region
// provably unread downstream); 2 = Keff=row0+256 (O-gemm, A lower-tri).
// EPI: 0 bf16; 1 +bias[row] bf16; 2 tril*scale bf16; 3 +bias[col] fp32.
template<int EPI>
__global__ __launch_bounds__(512, 1)
void gemm_nt2(const u16* __restrict__ A, const u16* __restrict__ B,
              void* __restrict__ Cv, int K, int lda, int ldb, int ldc,
              long asb, long asn, long bsb, long bsn, long csb, long csn,
              const float* __restrict__ bias, float scale, int tri)
{
  extern __shared__ __align__(16) char smem[];   // 4 * 32768 = 131072 B
  const int t = threadIdx.x;
  const int lane = t & 63;
  const int wave = t >> 6;          // 0..7
  const int wm = wave >> 2;         // 0..1
  const int wn = wave & 3;          // 0..3
  const long zb = blockIdx.z >> 3, zn = blockIdx.z & 7;
  A += zb*asb + zn*asn;
  B += zb*bsb + zn*bsn;
  const int row0 = blockIdx.y * 256, col0 = blockIdx.x * 256;

  // tri=1: block entirely above the diagonal -> identically zero after mask
  // and its output region is never read downstream (O-gemm reads only
  // k < row0+256). Block-uniform early exit BEFORE any barrier.
  if (tri == 1 && col0 >= row0 + 256) return;

  const int l15 = lane & 15, l4 = lane >> 4;

  // staging: thread t -> LDS slot t (16B), row = t>>2, chunk pos = t&3;
  // source chunk pre-swizzled: c_g = pos ^ g(row), g(r) = (r>>1)&3
  const int srow = t >> 2;                                // 0..127
  const int scol = (((t & 3) ^ ((srow >> 1) & 3)) * 8);   // elements
  const u16* gA = A + (long)(row0 + srow)*lda + scol;
  const u16* gB = B + (long)(col0 + srow)*ldb + scol;
  const long a128 = 128L*(long)lda, b128 = 128L*(long)ldb;
  const int ldst = t * 16;                                // byte slot

  // ds_read swizzled chunk: pos = l4 ^ g(row), g from l15
  const int csw = (l4 ^ ((l15 >> 1) & 3)) * 16;
  const int raw = (wm*128 + l15)*64 + csw;          // A read base (bytes)
  const int rbw = 16384 + (wn*64 + l15)*64 + csw;   // B read base

  f32x4 acc[8][4];
  #pragma unroll
  for (int m=0;m<8;m++)
    #pragma unroll
    for (int n=0;n<4;n++) acc[m][n] = (f32x4){0.f,0.f,0.f,0.f};

  int Keff = K;
  if (tri == 2) Keff = (row0 + 256 < K) ? (row0 + 256) : K;
  const int NT = Keff >> 5;   // 8 / 16 / 128 (multiple of 4)

#define STG_A(PA, BUF) \
  gload_lds16((PA),        smem + (BUF)*32768 +         ldst); \
  gload_lds16((PA) + a128, smem + (BUF)*32768 +  8192 + ldst);
#define STG_B(PB, BUF) \
  gload_lds16((PB),        smem + (BUF)*32768 + 16384 + ldst); \
  gload_lds16((PB) + b128, smem + (BUF)*32768 + 24576 + ldst);

#define WAITB(VM) \
  asm volatile("s_waitcnt vmcnt(" VM ")" ::: "memory"); \
  __builtin_amdgcn_s_barrier(); \
  asm volatile("" ::: "memory");

// Round-4-verified body + stage-issue split (S1 before cluster 1, S2 between).
#define COMPUTE(BUF, S1, S2) { \
  const char* base = smem + (BUF)*32768; \
  short8 bfr[4], afr[4]; \
  _Pragma("unroll") \
  for (int n=0;n<4;n++) bfr[n] = *(const short8*)(base + rbw + n*1024); \
  _Pragma("unroll") \
  for (int m=0;m<4;m++) afr[m] = *(const short8*)(base + raw + m*1024); \
  S1 \
  __builtin_amdgcn_s_setprio(1); \
  _Pragma("unroll") \
  for (int m=0;m<4;m++) \
    _Pragma("unroll") \
    for (int n=0;n<4;n++) \
      acc[m][n] = __builtin_amdgcn_mfma_f32_16x16x32_bf16(afr[m], bfr[n], acc[m][n],0,0,0); \
  __builtin_amdgcn_s_setprio(0); \
  _Pragma("unroll") \
  for (int m=0;m<4;m++) afr[m] = *(const short8*)(base + raw + (m+4)*1024); \
  S2 \
  __builtin_amdgcn_s_setprio(1); \
  _Pragma("unroll") \
  for (int m=0;m<4;m++) \
    _Pragma("unroll") \
    for (int n=0;n<4;n++) \
      acc[m+4][n] = __builtin_amdgcn_mfma_f32_16x16x32_bf16(afr[m], bfr[n], acc[m+4][n],0,0,0); \
  __builtin_amdgcn_s_setprio(0); \
}

  // prologue: 3 K-tiles in flight
  STG_A(gA,      0) STG_B(gB,      0)
  STG_A(gA + 32, 1) STG_B(gB + 32, 1)
  STG_A(gA + 64, 2) STG_B(gB + 64, 2)

  // main: tiles tk = tb..tb+3 (buffers 0..3); body(tk) stages tile tk+3
  #pragma unroll 1
  for (int tb = 0; tb < NT - 4; tb += 4){
    const u16* pa = gA + (long)(tb + 3)*32;
    const u16* pb = gB + (long)(tb + 3)*32;
    WAITB("8"); COMPUTE(0, STG_A(pa,      3), STG_B(pb,      3));
    WAITB("8"); COMPUTE(1, STG_A(pa + 32, 0), STG_B(pb + 32, 0));
    WAITB("8"); COMPUTE(2, STG_A(pa + 64, 1), STG_B(pb + 64, 1));
    WAITB("8"); COMPUTE(3, STG_A(pa + 96, 2), STG_B(pb + 96, 2));
  }
  // tail: tiles NT-4..NT-1 (buffers 0..3 since NT%4==0), one last stage
  {
    const u16* pa = gA + (long)(NT - 1)*32;
    const u16* pb = gB + (long)(NT - 1)*32;
    WAITB("8"); COMPUTE(0, STG_A(pa, 3), STG_B(pb, 3));
    WAITB("8"); COMPUTE(1, , );
    WAITB("4"); COMPUTE(2, , );
    WAITB("0"); COMPUTE(3, , );
  }
#undef STG_A
#undef STG_B
#undef WAITB
#undef COMPUTE

  // epilogue: C/D map col=lane&15, row=(lane>>4)*4+g  (HW-verified)
  if constexpr (EPI == 3){
    float* C = (float*)Cv;
    #pragma unroll
    for (int m=0;m<8;m++){
      int r0 = row0 + wm*128 + m*16 + l4*4;
      #pragma unroll
      for (int n=0;n<4;n++){
        int c = col0 + wn*64 + n*16 + l15;
        float bc = bias[c];
        #pragma unroll
        for (int g=0; g<4; g++)
          C[(long)(r0+g)*ldc + c] = acc[m][n][g] + bc;
      }
    }
  } else {
    u16* C = (u16*)Cv + zb*csb + zn*csn;
    #pragma unroll
    for (int m=0;m<8;m++){
      int r0 = row0 + wm*128 + m*16 + l4*4;
      #pragma unroll
      for (int n=0;n<4;n++){
        int c = col0 + wn*64 + n*16 + l15;
        #pragma unroll
        for (int g=0;g<4;g++){
          float v = acc[m][n][g];
          int r = r0 + g;
          if constexpr (EPI==1) v += bias[r];
          if constexpr (EPI==2) v = (c <= r) ? v*scale : 0.0f;
          C[(long)r*ldc + c] = f2bf(v);
        }
      }
    }
  }
}

// Workspace layout (bytes):
//   xb   @ 0          : 8192x4096 bf16
//   W1b  @ 67108864   : 4096x4096 bf16
//   W2b  @ 100663296  : 4096x4096 bf16
//   Lb   @ 134217728  : 8x512x512 bf16
//   Mb   @ 138412032  : 8x512x512 bf16
//   PtG  @ 142606336  : 4096x8192 bf16   PtG[c][r] = P_full[r][c]
//   MPt  @ 209715200  : 128x512x512 bf16 MPt[z][j][u] = MP[b,n,u,j]
//   Sb   @ 276824064  : 128x512x512 bf16
//   Ob   = MPt (reuse; MPt dead after S-gemm)

#define LDSB 131072

extern "C" void kernel_launch(void* const* d_in, const int* in_sizes, int n_in,
                              void* d_out, int out_size, void* d_ws, size_t ws_size,
                              hipStream_t stream)
{
  (void)in_sizes; (void)n_in; (void)out_size; (void)ws_size;
  const float* x   = (const float*)d_in[0];
  const float* W1  = (const float*)d_in[1];
  const float* b1  = (const float*)d_in[2];
  const float* pre = (const float*)d_in[3];
  const float* W2  = (const float*)d_in[4];
  const float* b2  = (const float*)d_in[5];
  float* out = (float*)d_out;
  char* ws = (char*)d_ws;

  u16* xb  = (u16*)(ws + 0L);
  u16* W1b = (u16*)(ws + 67108864L);
  u16* W2b = (u16*)(ws + 100663296L);
  u16* Lb  = (u16*)(ws + 134217728L);
  u16* Mb  = (u16*)(ws + 138412032L);
  u16* Pt  = (u16*)(ws + 142606336L);
  u16* MPt = (u16*)(ws + 209715200L);
  u16* Sb  = (u16*)(ws + 276824064L);
  u16* Ob  = MPt;  // reuse: MPt consumed by S-gemm before O-gemm writes

  hipFuncSetAttribute((const void*)gemm_nt2<0>, hipFuncAttributeMaxDynamicSharedMemorySize, LDSB);
  hipFuncSetAttribute((const void*)gemm_nt2<1>, hipFuncAttributeMaxDynamicSharedMemorySize, LDSB);
  hipFuncSetAttribute((const void*)gemm_nt2<2>, hipFuncAttributeMaxDynamicSharedMemorySize, LDSB);
  hipFuncSetAttribute((const void*)gemm_nt2<3>, hipFuncAttributeMaxDynamicSharedMemorySize, LDSB);

  // preps
  cast_bf16_kernel<<<4096,256,0,stream>>>(x,  xb,  4194304L);
  cast_bf16_kernel<<<4096,256,0,stream>>>(W1, W1b, 2097152L);
  cast_bf16_kernel<<<4096,256,0,stream>>>(W2, W2b, 2097152L);
  mask_cast_L_kernel<<<1024,256,0,stream>>>(pre, Lb);

  // M[n] = L[n] ·NT· L[n]          (8 batches, 512^3)
  gemm_nt2<0><<<dim3(2,2,8),512,LDSB,stream>>>(Lb, Lb, Mb, 512, 512,512,512,
      0, 262144, 0, 262144, 0, 262144, nullptr, 0.f, 0);

  // PtG = W1b ·NT· xb + b1[row]    (4096 x 8192, K=4096)
  gemm_nt2<1><<<dim3(32,16,1),512,LDSB,stream>>>(W1b, xb, Pt, 4096, 4096,4096,8192,
      0,0, 0,0, 0,0, b1, 0.f, 0);

  // MPt[z] = Pt(b,n) ·NT· M[n]     (128 batches, 512^3)
  gemm_nt2<0><<<dim3(2,2,128),512,LDSB,stream>>>(Pt, Mb, MPt, 512, 8192,512,512,
      512, 512L*8192, 0, 262144, 8L*262144, 262144, nullptr, 0.f, 0);

  // S[z] = Pt(b,n) ·NT· MPt[z], *1/sqrt(512), tril mask; skip upper blocks
  gemm_nt2<2><<<dim3(2,2,128),512,LDSB,stream>>>(Pt, MPt, Sb, 512, 8192,512,512,
      512, 512L*8192, 8L*262144, 262144, 8L*262144, 262144, nullptr, 0.04419417382f, 1);

  // O(b,n) = S[z] ·NT· Pt(b,n) -> Ob; S lower-tri => Keff = row0+256
  gemm_nt2<0><<<dim3(2,2,128),512,LDSB,stream>>>(Sb, Pt, Ob, 512, 512,8192,4096,
      8L*262144, 262144, 512, 512L*8192, 512L*4096, 512, nullptr, 0.f, 2);

  // Y = Ob ·NT· W2b + b2[col]      (8192 x 4096, K=4096, fp32 out)
  gemm_nt2<3><<<dim3(16,32,1),512,LDSB,stream>>>(Ob, W2b, out, 4096, 4096,4096,4096,
      0,0, 0,0, 0,0, b2, 0.f, 0);
}